// Round 3
// baseline (1178.018 us; speedup 1.0000x reference)
//
#include <hip/hip_runtime.h>
#include <hip/hip_bf16.h>

using bf16 = __hip_bfloat16;
typedef __attribute__((ext_vector_type(8))) short bfrag;   // 8 x bf16 (4 VGPRs)
typedef __attribute__((ext_vector_type(4))) float f32x4;

#define DEVINL __device__ __forceinline__

DEVINL unsigned short f2bf(float x) {
    bf16 b = __float2bfloat16(x);
    return *reinterpret_cast<unsigned short*>(&b);
}
DEVINL float bf2f(unsigned short u) {
    bf16 b = *reinterpret_cast<bf16*>(&u);
    return __bfloat162float(b);
}

DEVINL void gload_lds16(const bf16* g, bf16* l) {
    __builtin_amdgcn_global_load_lds(
        (const __attribute__((address_space(1))) void*)g,
        (__attribute__((address_space(3))) void*)l,
        16, 0, 0);
}

// ---------------------------------------------------------------------------
__global__ void init_acc(double* acc) {
    if (threadIdx.x < 2) acc[threadIdx.x] = 0.0;
}

// ---------------------------------------------------------------------------
// transpose + cast: W[K][N] f32 -> WT[N][K] bf16
// ---------------------------------------------------------------------------
__global__ void transpose_cast(const float* __restrict__ W, bf16* __restrict__ WT,
                               int K, int N) {
    __shared__ float tile[32][33];
    int n0 = blockIdx.x * 32, k0 = blockIdx.y * 32;
    int tx = threadIdx.x, ty0 = threadIdx.y;   // block 32 x 8
#pragma unroll
    for (int i = 0; i < 4; ++i) {
        int ty = ty0 + i * 8;
        tile[ty][tx] = W[(size_t)(k0 + ty) * N + n0 + tx];
    }
    __syncthreads();
#pragma unroll
    for (int i = 0; i < 4; ++i) {
        int ty = ty0 + i * 8;
        WT[(size_t)(n0 + ty) * K + k0 + tx] = __float2bfloat16(tile[tx][ty]);
    }
}

// ---------------------------------------------------------------------------
// gather sampled rows (circular-buffer: rows <8192 come from hidden flat)
// ---------------------------------------------------------------------------
__global__ void gather_cast(const float* __restrict__ hidden,
                            const float* __restrict__ memory,
                            const int* __restrict__ idx,
                            bf16* __restrict__ samples) {
    int s = blockIdx.x;
    int r = idx[s];
    const float* src = (r < 8192) ? hidden + (size_t)r * 4096
                                  : memory + (size_t)r * 4096;
    unsigned short* dst = (unsigned short*)(samples + (size_t)s * 4096);
#pragma unroll
    for (int c = threadIdx.x * 4; c < 4096; c += 1024) {
        float4 v = *(const float4*)(src + c);
        ushort4 o;
        o.x = f2bf(v.x); o.y = f2bf(v.y); o.z = f2bf(v.z); o.w = f2bf(v.w);
        *(ushort4*)(dst + c) = o;
    }
}

// ---------------------------------------------------------------------------
// GEMM  C[M,N] = A[M,K] @ BT[N,K]^T  (+bias, fused epilogue)
// 256x256 tile, BK=32, 8 waves (2M x 4N), 4-deep LDS ring (128 KiB),
// counted vmcnt(8): 2 future K-tiles stay in flight across the single
// per-iter fused wait+barrier. NO lgkm fence — compiler interleaves
// ds_read/MFMA with fine-grained lgkmcnt (m97 evidence). XOR swizzle
// blk^=(row>>1)&3 both sides (conflict-free, verified R2).
// EPI: 0 = gelu(exact)->bf16 ; 1 = store bf16 ; 3 = recon MSE reduce
// ---------------------------------------------------------------------------
template <int EPI>
__global__ __launch_bounds__(512, 2)
void gemm256(const bf16* __restrict__ A, const bf16* __restrict__ BT,
             const float* __restrict__ bias, bf16* __restrict__ C,
             const bf16* __restrict__ S, double* __restrict__ accum,
             int M, int N, int K, int MT) {
    __shared__ __align__(16) bf16 lds[4][2][256 * 32];

    const int tid  = threadIdx.x;
    const int lane = tid & 63;
    const int wave = tid >> 6;      // 0..7
    const int wr   = wave >> 2;     // 0..1  (M half)
    const int wc   = wave & 3;      // 0..3  (N quarter)

    // XCD-aware bijective chunked decode (gridDim.x % 8 == 0 for all calls)
    const int nwg  = gridDim.x;
    const int cpx  = nwg >> 3;
    const int work = (blockIdx.x & 7) * cpx + (blockIdx.x >> 3);
    const int ntile = work / MT;
    const int mtile = work - ntile * MT;
    const int m0 = mtile * 256;
    const int n0 = ntile * 256;

    auto stage = [&](int buf, int kt) {
        const size_t kb = (size_t)kt * 32;
        const int r = tid >> 2;          // 0..127
        const int b = tid & 3;
#pragma unroll
        for (int i = 0; i < 2; ++i) {
            int row = i * 128 + r;
            int bg  = b ^ ((row >> 1) & 3);          // pre-swizzled source
            gload_lds16(A + (size_t)(m0 + row) * K + kb + (size_t)bg * 8,
                        &lds[buf][0][row * 32 + b * 8]);   // linear dest
        }
#pragma unroll
        for (int i = 0; i < 2; ++i) {
            int row = i * 128 + r;
            int bg  = b ^ ((row >> 1) & 3);
            gload_lds16(BT + (size_t)(n0 + row) * K + kb + (size_t)bg * 8,
                        &lds[buf][1][row * 32 + b * 8]);
        }
    };

    const int g = lane >> 4;            // k-group of the MFMA fragment
    auto rdA = [&](int buf, int m) -> bfrag {
        int row = wr * 128 + m * 16 + (lane & 15);
        int e   = row * 32 + ((g ^ ((row >> 1) & 3)) << 3);   // swizzled read
        return *(const bfrag*)&lds[buf][0][e];
    };
    auto rdB = [&](int buf, int n) -> bfrag {
        int row = wc * 64 + n * 16 + (lane & 15);
        int e   = row * 32 + ((g ^ ((row >> 1) & 3)) << 3);
        return *(const bfrag*)&lds[buf][1][e];
    };

    f32x4 acc[8][4] = {};

    const int nk = K >> 5;              // >= 32 for all calls
    stage(0, 0); stage(1, 1); stage(2, 2);
    asm volatile("s_waitcnt vmcnt(8)\n\ts_barrier" ::: "memory");

    for (int t = 0; t < nk; ++t) {
        const int cb = t & 3;
        if (t + 3 < nk) stage((t + 3) & 3, t + 3);     // VMEM issue leads
        bfrag af[8], bfv[4];
#pragma unroll
        for (int m = 0; m < 8; ++m) af[m] = rdA(cb, m);
#pragma unroll
        for (int n = 0; n < 4; ++n) bfv[n] = rdB(cb, n);
        __builtin_amdgcn_s_setprio(1);
#pragma unroll
        for (int m = 0; m < 8; ++m)
#pragma unroll
            for (int n = 0; n < 4; ++n)
                acc[m][n] = __builtin_amdgcn_mfma_f32_16x16x32_bf16(
                    af[m], bfv[n], acc[m][n], 0, 0, 0);
        __builtin_amdgcn_s_setprio(0);
        // fused counted-wait + barrier (memory clobber pins ds_reads on
        // both sides — prevents hoisting next iter's reads past the join)
        if (t + 3 < nk)
            asm volatile("s_waitcnt vmcnt(8)\n\ts_barrier" ::: "memory");
        else if (t + 2 < nk)
            asm volatile("s_waitcnt vmcnt(4)\n\ts_barrier" ::: "memory");
        else if (t + 1 < nk)
            asm volatile("s_waitcnt vmcnt(0)\n\ts_barrier" ::: "memory");
        else
            asm volatile("s_barrier" ::: "memory");
    }

    // epilogue: C/D layout col=lane&15, row=(lane>>4)*4+j  [m89-verified]
    float lsum = 0.f;
#pragma unroll
    for (int m = 0; m < 8; ++m) {
        int row0 = m0 + wr * 128 + m * 16 + (lane >> 4) * 4;
#pragma unroll
        for (int n = 0; n < 4; ++n) {
            int col = n0 + wc * 64 + n * 16 + (lane & 15);
            float bv = bias[col];
#pragma unroll
            for (int j = 0; j < 4; ++j) {
                float v  = acc[m][n][j] + bv;
                int row  = row0 + j;
                if (EPI == 0) {
                    float ge = 0.5f * v * (1.f + erff(v * 0.70710678118f));
                    C[(size_t)row * N + col] = __float2bfloat16(ge);
                } else if (EPI == 1) {
                    C[(size_t)row * N + col] = __float2bfloat16(v);
                } else {
                    float d = v - __bfloat162float(S[(size_t)row * N + col]);
                    lsum += d * d;
                }
            }
        }
    }

    if (EPI == 3) {
        __shared__ float red[8];
        float v = lsum;
#pragma unroll
        for (int o = 32; o > 0; o >>= 1) v += __shfl_down(v, o);
        if (lane == 0) red[wave] = v;
        __syncthreads();
        if (tid == 0) {
            double t = 0.0;
#pragma unroll
            for (int w = 0; w < 8; ++w) t += (double)red[w];
            atomicAdd(accum, t);
        }
    }
}

// ---------------------------------------------------------------------------
// reparameterization + KL partial sums
// ---------------------------------------------------------------------------
__global__ void z_kl_kernel(const bf16* __restrict__ enc,
                            const float* __restrict__ eps,
                            bf16* __restrict__ z, double* __restrict__ acc) {
    int s = blockIdx.x;
    int c = threadIdx.x * 4;
    ushort4 muu = *(const ushort4*)((const unsigned short*)(enc + (size_t)s * 2048 + c));
    ushort4 lvu = *(const ushort4*)((const unsigned short*)(enc + (size_t)s * 2048 + 1024 + c));
    float4 ev   = *(const float4*)(eps + (size_t)s * 1024 + c);

    float kl = 0.f;
    ushort4 zo;
    {
        float mu = bf2f(muu.x), lv = bf2f(lvu.x), el = expf(lv);
        zo.x = f2bf(mu + sqrtf(el) * ev.x);
        kl += 1.f + lv - mu * mu - el;
    }
    {
        float mu = bf2f(muu.y), lv = bf2f(lvu.y), el = expf(lv);
        zo.y = f2bf(mu + sqrtf(el) * ev.y);
        kl += 1.f + lv - mu * mu - el;
    }
    {
        float mu = bf2f(muu.z), lv = bf2f(lvu.z), el = expf(lv);
        zo.z = f2bf(mu + sqrtf(el) * ev.z);
        kl += 1.f + lv - mu * mu - el;
    }
    {
        float mu = bf2f(muu.w), lv = bf2f(lvu.w), el = expf(lv);
        zo.w = f2bf(mu + sqrtf(el) * ev.w);
        kl += 1.f + lv - mu * mu - el;
    }
    *(ushort4*)((unsigned short*)(z + (size_t)s * 1024 + c)) = zo;

    __shared__ float red[4];
    float v = kl;
#pragma unroll
    for (int o = 32; o > 0; o >>= 1) v += __shfl_down(v, o);
    int lane = threadIdx.x & 63, wave = threadIdx.x >> 6;
    if (lane == 0) red[wave] = v;
    __syncthreads();
    if (threadIdx.x == 0) {
        double t = (double)red[0] + (double)red[1] +
                   (double)red[2] + (double)red[3];
        atomicAdd(acc + 1, t);
    }
}

// ---------------------------------------------------------------------------
__global__ void finalize_kernel(const double* __restrict__ acc,
                                float* __restrict__ out) {
    if (threadIdx.x == 0)
        out[0] = (float)(acc[0] * (1.0 / (16384.0 * 4096.0)) - 0.0005 * acc[1]);
}

// ---------------------------------------------------------------------------
extern "C" void kernel_launch(void* const* d_in, const int* in_sizes, int n_in,
                              void* d_out, int out_size, void* d_ws, size_t ws_size,
                              hipStream_t stream) {
    const float* hidden = (const float*)d_in[0];
    const float* memory = (const float*)d_in[1];
    const int*   idx    = (const int*)d_in[2];
    const float* eps    = (const float*)d_in[3];
    const float* W1     = (const float*)d_in[4];
    const float* b1     = (const float*)d_in[5];
    const float* W2     = (const float*)d_in[6];
    const float* b2     = (const float*)d_in[7];
    const float* Wd1    = (const float*)d_in[8];
    const float* bd1    = (const float*)d_in[9];
    const float* Wd2    = (const float*)d_in[10];
    const float* bd2    = (const float*)d_in[11];

    char* ws = (char*)d_ws;
    double* acc   = (double*)ws;                                   // 16 B
    bf16* samples = (bf16*)(ws + 256);                             // 16384x4096
    bf16* h       = samples + (size_t)16384 * 4096;                // 16384x2048 (reused for hd)
    bf16* enc     = h       + (size_t)16384 * 2048;                // 16384x2048
    bf16* z       = enc     + (size_t)16384 * 2048;                // 16384x1024
    bf16* W1T     = z       + (size_t)16384 * 1024;                // 2048x4096
    bf16* W2T     = W1T     + (size_t)2048 * 4096;                 // 2048x2048
    bf16* Wd1T    = W2T     + (size_t)2048 * 2048;                 // 2048x1024
    bf16* Wd2T    = Wd1T    + (size_t)2048 * 1024;                 // 4096x2048

    init_acc<<<1, 64, 0, stream>>>(acc);

    dim3 tb(32, 8);
    transpose_cast<<<dim3(2048 / 32, 4096 / 32), tb, 0, stream>>>(W1, W1T, 4096, 2048);
    transpose_cast<<<dim3(2048 / 32, 2048 / 32), tb, 0, stream>>>(W2, W2T, 2048, 2048);
    transpose_cast<<<dim3(2048 / 32, 1024 / 32), tb, 0, stream>>>(Wd1, Wd1T, 1024, 2048);
    transpose_cast<<<dim3(4096 / 32, 2048 / 32), tb, 0, stream>>>(Wd2, Wd2T, 2048, 4096);

    gather_cast<<<16384, 256, 0, stream>>>(hidden, memory, idx, samples);

    // h = gelu(samples @ W1 + b1)          M=16384 N=2048 K=4096
    gemm256<0><<<512, 512, 0, stream>>>(samples, W1T, b1, h, nullptr, nullptr,
                                        16384, 2048, 4096, 64);
    // enc = h @ W2 + b2                    K=2048
    gemm256<1><<<512, 512, 0, stream>>>(h, W2T, b2, enc, nullptr, nullptr,
                                        16384, 2048, 2048, 64);
    // z = mu + exp(0.5 lv) * eps ; kl partials
    z_kl_kernel<<<16384, 256, 0, stream>>>(enc, eps, z, acc);
    // hd = gelu(z @ Wd1 + bd1)             K=1024 (reuses h buffer)
    gemm256<0><<<512, 512, 0, stream>>>(z, Wd1T, bd1, h, nullptr, nullptr,
                                        16384, 2048, 1024, 64);
    // rec = hd @ Wd2 + bd2 ; fused recon MSE vs samples   N=4096 K=2048
    gemm256<3><<<1024, 512, 0, stream>>>(h, Wd2T, bd2, nullptr, samples, acc,
                                         16384, 4096, 2048, 64);

    finalize_kernel<<<1, 64, 0, stream>>>(acc, (float*)d_out);
}

// Round 4
// 1080.244 us; speedup vs baseline: 1.0905x; 1.0905x over previous
//
#include <hip/hip_runtime.h>
#include <hip/hip_bf16.h>

using bf16 = __hip_bfloat16;
typedef __attribute__((ext_vector_type(8))) short bfrag;   // 8 x bf16 (4 VGPRs)
typedef __attribute__((ext_vector_type(4))) float f32x4;

#define DEVINL __device__ __forceinline__

DEVINL unsigned short f2bf(float x) {
    bf16 b = __float2bfloat16(x);
    return *reinterpret_cast<unsigned short*>(&b);
}
DEVINL float bf2f(unsigned short u) {
    bf16 b = *reinterpret_cast<bf16*>(&u);
    return __bfloat162float(b);
}

DEVINL void gload_lds16(const bf16* g, bf16* l) {
    __builtin_amdgcn_global_load_lds(
        (const __attribute__((address_space(1))) void*)g,
        (__attribute__((address_space(3))) void*)l,
        16, 0, 0);
}

#define BAR()   asm volatile("s_barrier" ::: "memory")
#define LGKM0() asm volatile("s_waitcnt lgkmcnt(0)" ::: "memory")

// ---------------------------------------------------------------------------
__global__ void init_acc(double* acc) {
    if (threadIdx.x < 2) acc[threadIdx.x] = 0.0;
}

// ---------------------------------------------------------------------------
// transpose + cast: W[K][N] f32 -> WT[N][K] bf16
// ---------------------------------------------------------------------------
__global__ void transpose_cast(const float* __restrict__ W, bf16* __restrict__ WT,
                               int K, int N) {
    __shared__ float tile[32][33];
    int n0 = blockIdx.x * 32, k0 = blockIdx.y * 32;
    int tx = threadIdx.x, ty0 = threadIdx.y;   // block 32 x 8
#pragma unroll
    for (int i = 0; i < 4; ++i) {
        int ty = ty0 + i * 8;
        tile[ty][tx] = W[(size_t)(k0 + ty) * N + n0 + tx];
    }
    __syncthreads();
#pragma unroll
    for (int i = 0; i < 4; ++i) {
        int ty = ty0 + i * 8;
        WT[(size_t)(n0 + ty) * K + k0 + tx] = __float2bfloat16(tile[tx][ty]);
    }
}

// ---------------------------------------------------------------------------
// gather sampled rows (circular-buffer: rows <8192 come from hidden flat)
// ---------------------------------------------------------------------------
__global__ void gather_cast(const float* __restrict__ hidden,
                            const float* __restrict__ memory,
                            const int* __restrict__ idx,
                            bf16* __restrict__ samples) {
    int s = blockIdx.x;
    int r = idx[s];
    const float* src = (r < 8192) ? hidden + (size_t)r * 4096
                                  : memory + (size_t)r * 4096;
    unsigned short* dst = (unsigned short*)(samples + (size_t)s * 4096);
#pragma unroll
    for (int c = threadIdx.x * 4; c < 4096; c += 1024) {
        float4 v = *(const float4*)(src + c);
        ushort4 o;
        o.x = f2bf(v.x); o.y = f2bf(v.y); o.z = f2bf(v.z); o.w = f2bf(v.w);
        *(ushort4*)(dst + c) = o;
    }
}

// ---------------------------------------------------------------------------
// 8-phase GEMM (m201 template port)  C[M,N] = A[M,K] @ BT[N,K]^T (+bias, epi)
// BM=BN=256, BK=64, 2 K-tiles/iter, 8 waves (2Mx4N), LDS 2x(A+B)[256][64]
// = 128 KiB. Swizzle kb^=(row&7) both sides (involution, bank-uniform).
// Staging ledger (steady state, iter j; ta=2j in buf0, tb=2j+1 in buf1):
//   ph1: read A0,B0(buf0)  stage buf1.A0[tb]    (buf1.A free since ph8 j-1)
//   ph2: read B1(buf0)     stage buf1.A1[tb]
//   ph3: read A1(buf0)     stage buf0.B0[ta+2]  (buf0.B reads done ph2)
//   ph4: —                 stage buf0.B1[ta+2]  then VMCNT(4)+BAR
//        (retires ph7'/ph8' [buf1.B=tb] + ph1/ph2 [buf1.A=tb] -> buf1 ready)
//   ph5: read A0,B0(buf1)  stage buf0.A0[ta+2]  (buf0.A reads done ph4)
//   ph6: read B1(buf1)     stage buf0.A1[ta+2]
//   ph7: read A1(buf1)     stage buf1.B0[tb+2]  (buf1.B reads done ph6)
//   ph8: —                 stage buf1.B1[tb+2]  then VMCNT(4)+BAR
//        (retires ph3..ph6 [buf0=ta+2] -> buf0 ready for next ph1)
// Prologue: t0 full + t1.B (6 half-tiles, 12 loads), vmcnt(4)+bar.
// Tail: last iter stages guard off (kt>=nk2); ph4 uses vmcnt(0); ph8 none.
// EPI: 0 = gelu(exact)->bf16 ; 1 = store bf16 ; 3 = recon MSE reduce
// ---------------------------------------------------------------------------
template <int EPI>
__global__ __launch_bounds__(512, 2)
void gemm8p(const bf16* __restrict__ A, const bf16* __restrict__ BT,
            const float* __restrict__ bias, bf16* __restrict__ C,
            const bf16* __restrict__ S, double* __restrict__ accum,
            int M, int N, int K, int MT) {
    __shared__ __align__(16) bf16 lds[2][2][256 * 64];   // [buf][A/B][row][k]

    const int tid  = threadIdx.x;
    const int lane = tid & 63;
    const int wave = tid >> 6;      // 0..7
    const int wr   = wave >> 2;     // 0..1
    const int wc   = wave & 3;      // 0..3

    // XCD-aware bijective chunked decode (gridDim.x % 8 == 0 always here)
    const int nwg  = gridDim.x;
    const int cpx  = nwg >> 3;
    const int work = (blockIdx.x & 7) * cpx + (blockIdx.x >> 3);
    const int ntile = work / MT;
    const int mtile = work - ntile * MT;
    const int m0 = mtile * 256;
    const int n0 = ntile * 256;

    const int nk2 = K >> 6;         // # K-tiles of 64 (even: 16/32/64)

    // staging map: thread t -> (row = h*128 + j*64 + (t>>3), kb = t&7)
    // LDS dest linear in t (16B/thread); global source pre-swizzled.
    const int srow = tid >> 3;      // 0..63
    const int skb  = tid & 7;

    auto stage2 = [&](int buf, int mat, int h, int kt) {
        if (kt >= nk2) return;
        const bf16* G = mat ? BT : A;
        const int base0 = mat ? n0 : m0;
        const size_t kcol = (size_t)kt * 64;
#pragma unroll
        for (int j = 0; j < 2; ++j) {
            int row = h * 128 + j * 64 + srow;
            int kbg = skb ^ (row & 7);            // inverse-swizzled source
            gload_lds16(G + (size_t)(base0 + row) * K + kcol + (size_t)kbg * 8,
                        &lds[buf][mat][row * 64 + skb * 8]);  // linear dest
        }
    };

    const int g   = lane >> 4;      // k-group 0..3
    const int l15 = lane & 15;
    auto rdA = [&](int buf, int mf, int ks) -> bfrag {
        int row = wr * 128 + mf * 16 + l15;
        int kb  = (ks * 4 + g) ^ (row & 7);       // swizzled read
        return *(const bfrag*)&lds[buf][0][row * 64 + kb * 8];
    };
    auto rdB = [&](int buf, int nf, int ks) -> bfrag {
        int row = wc * 64 + nf * 16 + l15;
        int kb  = (ks * 4 + g) ^ (row & 7);
        return *(const bfrag*)&lds[buf][1][row * 64 + kb * 8];
    };

    f32x4 acc[8][4] = {};
    bfrag af[4][2], b0f[2][2], b1f[2][2];

    auto mfma_quad = [&](int mh, int nh, bfrag (&BF)[2][2]) {
        __builtin_amdgcn_s_setprio(1);
#pragma unroll
        for (int ks = 0; ks < 2; ++ks)
#pragma unroll
            for (int mi = 0; mi < 4; ++mi)
#pragma unroll
                for (int nj = 0; nj < 2; ++nj)
                    acc[mh * 4 + mi][nh * 2 + nj] =
                        __builtin_amdgcn_mfma_f32_16x16x32_bf16(
                            af[mi][ks], BF[nj][ks],
                            acc[mh * 4 + mi][nh * 2 + nj], 0, 0, 0);
        __builtin_amdgcn_s_setprio(0);
    };

    // ---- prologue: buf0 = tile0 (B,A), buf1 = tile1 (B only) = 12 loads
    stage2(0, 1, 0, 0); stage2(0, 1, 1, 0);
    stage2(0, 0, 0, 0); stage2(0, 0, 1, 0);
    stage2(1, 1, 0, 1); stage2(1, 1, 1, 1);
    asm volatile("s_waitcnt vmcnt(4)\n\ts_barrier" ::: "memory");  // buf0 landed

    const int niter = nk2 >> 1;
    for (int it = 0; it < niter; ++it) {
        const int ta = 2 * it, tb = 2 * it + 1;
        const bool last = (it == niter - 1);

        // ---- ph1 ----
#pragma unroll
        for (int mi = 0; mi < 4; ++mi) {
            af[mi][0] = rdA(0, mi, 0); af[mi][1] = rdA(0, mi, 1);
        }
#pragma unroll
        for (int nj = 0; nj < 2; ++nj) {
            b0f[nj][0] = rdB(0, nj, 0); b0f[nj][1] = rdB(0, nj, 1);
        }
        stage2(1, 0, 0, tb);
        asm volatile("s_waitcnt lgkmcnt(8)" :::);
        BAR(); LGKM0();
        mfma_quad(0, 0, b0f);
        BAR();
        // ---- ph2 ----
#pragma unroll
        for (int nj = 0; nj < 2; ++nj) {
            b1f[nj][0] = rdB(0, nj + 2, 0); b1f[nj][1] = rdB(0, nj + 2, 1);
        }
        stage2(1, 0, 1, tb);
        BAR(); LGKM0();
        mfma_quad(0, 1, b1f);
        BAR();
        // ---- ph3 ----
#pragma unroll
        for (int mi = 0; mi < 4; ++mi) {
            af[mi][0] = rdA(0, mi + 4, 0); af[mi][1] = rdA(0, mi + 4, 1);
        }
        stage2(0, 1, 0, ta + 2);
        BAR(); LGKM0();
        mfma_quad(1, 0, b0f);
        BAR();
        // ---- ph4 ----
        stage2(0, 1, 1, ta + 2);
        BAR(); LGKM0();
        mfma_quad(1, 1, b1f);
        if (last) asm volatile("s_waitcnt vmcnt(0)\n\ts_barrier" ::: "memory");
        else      asm volatile("s_waitcnt vmcnt(4)\n\ts_barrier" ::: "memory");
        // ---- ph5 ----
#pragma unroll
        for (int mi = 0; mi < 4; ++mi) {
            af[mi][0] = rdA(1, mi, 0); af[mi][1] = rdA(1, mi, 1);
        }
#pragma unroll
        for (int nj = 0; nj < 2; ++nj) {
            b0f[nj][0] = rdB(1, nj, 0); b0f[nj][1] = rdB(1, nj, 1);
        }
        stage2(0, 0, 0, ta + 2);
        asm volatile("s_waitcnt lgkmcnt(8)" :::);
        BAR(); LGKM0();
        mfma_quad(0, 0, b0f);
        BAR();
        // ---- ph6 ----
#pragma unroll
        for (int nj = 0; nj < 2; ++nj) {
            b1f[nj][0] = rdB(1, nj + 2, 0); b1f[nj][1] = rdB(1, nj + 2, 1);
        }
        stage2(0, 0, 1, ta + 2);
        BAR(); LGKM0();
        mfma_quad(0, 1, b1f);
        BAR();
        // ---- ph7 ----
#pragma unroll
        for (int mi = 0; mi < 4; ++mi) {
            af[mi][0] = rdA(1, mi + 4, 0); af[mi][1] = rdA(1, mi + 4, 1);
        }
        stage2(1, 1, 0, tb + 2);
        BAR(); LGKM0();
        mfma_quad(1, 0, b0f);
        BAR();
        // ---- ph8 ----
        stage2(1, 1, 1, tb + 2);
        BAR(); LGKM0();
        mfma_quad(1, 1, b1f);
        if (!last)
            asm volatile("s_waitcnt vmcnt(4)\n\ts_barrier" ::: "memory");
    }

    // epilogue: C/D layout col=lane&15, row=(lane>>4)*4+j  [m89-verified]
    float lsum = 0.f;
#pragma unroll
    for (int m = 0; m < 8; ++m) {
        int row0 = m0 + wr * 128 + m * 16 + (lane >> 4) * 4;
#pragma unroll
        for (int n = 0; n < 4; ++n) {
            int col = n0 + wc * 64 + n * 16 + (lane & 15);
            float bv = bias[col];
#pragma unroll
            for (int j = 0; j < 4; ++j) {
                float v  = acc[m][n][j] + bv;
                int row  = row0 + j;
                if (EPI == 0) {
                    float ge = 0.5f * v * (1.f + erff(v * 0.70710678118f));
                    C[(size_t)row * N + col] = __float2bfloat16(ge);
                } else if (EPI == 1) {
                    C[(size_t)row * N + col] = __float2bfloat16(v);
                } else {
                    float d = v - __bfloat162float(S[(size_t)row * N + col]);
                    lsum += d * d;
                }
            }
        }
    }

    if (EPI == 3) {
        __shared__ float red[8];
        float v = lsum;
#pragma unroll
        for (int o = 32; o > 0; o >>= 1) v += __shfl_down(v, o);
        if (lane == 0) red[wave] = v;
        __syncthreads();
        if (tid == 0) {
            double t = 0.0;
#pragma unroll
            for (int w = 0; w < 8; ++w) t += (double)red[w];
            atomicAdd(accum, t);
        }
    }
}

// ---------------------------------------------------------------------------
// reparameterization + KL partial sums
// ---------------------------------------------------------------------------
__global__ void z_kl_kernel(const bf16* __restrict__ enc,
                            const float* __restrict__ eps,
                            bf16* __restrict__ z, double* __restrict__ acc) {
    int s = blockIdx.x;
    int c = threadIdx.x * 4;
    ushort4 muu = *(const ushort4*)((const unsigned short*)(enc + (size_t)s * 2048 + c));
    ushort4 lvu = *(const ushort4*)((const unsigned short*)(enc + (size_t)s * 2048 + 1024 + c));
    float4 ev   = *(const float4*)(eps + (size_t)s * 1024 + c);

    float kl = 0.f;
    ushort4 zo;
    {
        float mu = bf2f(muu.x), lv = bf2f(lvu.x), el = expf(lv);
        zo.x = f2bf(mu + sqrtf(el) * ev.x);
        kl += 1.f + lv - mu * mu - el;
    }
    {
        float mu = bf2f(muu.y), lv = bf2f(lvu.y), el = expf(lv);
        zo.y = f2bf(mu + sqrtf(el) * ev.y);
        kl += 1.f + lv - mu * mu - el;
    }
    {
        float mu = bf2f(muu.z), lv = bf2f(lvu.z), el = expf(lv);
        zo.z = f2bf(mu + sqrtf(el) * ev.z);
        kl += 1.f + lv - mu * mu - el;
    }
    {
        float mu = bf2f(muu.w), lv = bf2f(lvu.w), el = expf(lv);
        zo.w = f2bf(mu + sqrtf(el) * ev.w);
        kl += 1.f + lv - mu * mu - el;
    }
    *(ushort4*)((unsigned short*)(z + (size_t)s * 1024 + c)) = zo;

    __shared__ float red[4];
    float v = kl;
#pragma unroll
    for (int o = 32; o > 0; o >>= 1) v += __shfl_down(v, o);
    int lane = threadIdx.x & 63, wave = threadIdx.x >> 6;
    if (lane == 0) red[wave] = v;
    __syncthreads();
    if (threadIdx.x == 0) {
        double t = (double)red[0] + (double)red[1] +
                   (double)red[2] + (double)red[3];
        atomicAdd(acc + 1, t);
    }
}

// ---------------------------------------------------------------------------
__global__ void finalize_kernel(const double* __restrict__ acc,
                                float* __restrict__ out) {
    if (threadIdx.x == 0)
        out[0] = (float)(acc[0] * (1.0 / (16384.0 * 4096.0)) - 0.0005 * acc[1]);
}

// ---------------------------------------------------------------------------
extern "C" void kernel_launch(void* const* d_in, const int* in_sizes, int n_in,
                              void* d_out, int out_size, void* d_ws, size_t ws_size,
                              hipStream_t stream) {
    const float* hidden = (const float*)d_in[0];
    const float* memory = (const float*)d_in[1];
    const int*   idx    = (const int*)d_in[2];
    const float* eps    = (const float*)d_in[3];
    const float* W1     = (const float*)d_in[4];
    const float* b1     = (const float*)d_in[5];
    const float* W2     = (const float*)d_in[6];
    const float* b2     = (const float*)d_in[7];
    const float* Wd1    = (const float*)d_in[8];
    const float* bd1    = (const float*)d_in[9];
    const float* Wd2    = (const float*)d_in[10];
    const float* bd2    = (const float*)d_in[11];

    char* ws = (char*)d_ws;
    double* acc   = (double*)ws;                                   // 16 B
    bf16* samples = (bf16*)(ws + 256);                             // 16384x4096
    bf16* h       = samples + (size_t)16384 * 4096;                // 16384x2048 (reused for hd)
    bf16* enc     = h       + (size_t)16384 * 2048;                // 16384x2048
    bf16* z       = enc     + (size_t)16384 * 2048;                // 16384x1024
    bf16* W1T     = z       + (size_t)16384 * 1024;                // 2048x4096
    bf16* W2T     = W1T     + (size_t)2048 * 4096;                 // 2048x2048
    bf16* Wd1T    = W2T     + (size_t)2048 * 2048;                 // 2048x1024
    bf16* Wd2T    = Wd1T    + (size_t)2048 * 1024;                 // 4096x2048

    init_acc<<<1, 64, 0, stream>>>(acc);

    dim3 tb(32, 8);
    transpose_cast<<<dim3(2048 / 32, 4096 / 32), tb, 0, stream>>>(W1, W1T, 4096, 2048);
    transpose_cast<<<dim3(2048 / 32, 2048 / 32), tb, 0, stream>>>(W2, W2T, 2048, 2048);
    transpose_cast<<<dim3(2048 / 32, 1024 / 32), tb, 0, stream>>>(Wd1, Wd1T, 1024, 2048);
    transpose_cast<<<dim3(4096 / 32, 2048 / 32), tb, 0, stream>>>(Wd2, Wd2T, 2048, 4096);

    gather_cast<<<16384, 256, 0, stream>>>(hidden, memory, idx, samples);

    // h = gelu(samples @ W1 + b1)          M=16384 N=2048 K=4096
    gemm8p<0><<<512, 512, 0, stream>>>(samples, W1T, b1, h, nullptr, nullptr,
                                       16384, 2048, 4096, 64);
    // enc = h @ W2 + b2                    K=2048
    gemm8p<1><<<512, 512, 0, stream>>>(h, W2T, b2, enc, nullptr, nullptr,
                                       16384, 2048, 2048, 64);
    // z = mu + exp(0.5 lv) * eps ; kl partials
    z_kl_kernel<<<16384, 256, 0, stream>>>(enc, eps, z, acc);
    // hd = gelu(z @ Wd1 + bd1)             K=1024 (reuses h buffer)
    gemm8p<0><<<512, 512, 0, stream>>>(z, Wd1T, bd1, h, nullptr, nullptr,
                                       16384, 2048, 1024, 64);
    // rec = hd @ Wd2 + bd2 ; fused recon MSE vs samples   N=4096 K=2048
    gemm8p<3><<<1024, 512, 0, stream>>>(h, Wd2T, bd2, nullptr, samples, acc,
                                        16384, 4096, 2048, 64);

    finalize_kernel<<<1, 64, 0, stream>>>(acc, (float*)d_out);
}